// Round 1
// baseline (26348.431 us; speedup 1.0000x reference)
//
#include <hip/hip_runtime.h>
#include <stdint.h>

#define BB 128      // batch
#define TT 150      // seq len
#define HH 512      // hidden
#define AA 512      // attention dim
#define SS 1024     // 2A (softmax length)
#define VV 600      // vocab / output size
#define KCAT 1112   // V + H
#define G3 1536     // 3H

typedef short s8v __attribute__((ext_vector_type(8)));   // 8 x bf16 (4 VGPR)
typedef float f4v __attribute__((ext_vector_type(4)));   // 4 x f32 acc

__device__ __forceinline__ ushort f2bf(float f) {
    uint32_t u = __builtin_bit_cast(uint32_t, f);
    uint32_t r = (u + 0x7fffu + ((u >> 16) & 1u)) >> 16;  // RNE
    return (ushort)r;
}
__device__ __forceinline__ float bflo(uint32_t x) {
    uint32_t u = (x & 0xffffu) << 16;
    return __builtin_bit_cast(float, u);
}
__device__ __forceinline__ float bfhi(uint32_t x) {
    uint32_t u = x & 0xffff0000u;
    return __builtin_bit_cast(float, u);
}

// ---------------- conversion: fp32 -> bf16 (vectorized) ----------------
__global__ void k_cvt4(const float4* __restrict__ src, ushort* __restrict__ dst, long n4) {
    long i = (long)blockIdx.x * blockDim.x + threadIdx.x;
    long st = (long)gridDim.x * blockDim.x;
    for (; i < n4; i += st) {
        float4 v = src[i];
        ushort4 o;
        o.x = f2bf(v.x); o.y = f2bf(v.y); o.z = f2bf(v.z); o.w = f2bf(v.w);
        *(ushort4*)(dst + i * 4) = o;
    }
}

// ---------------- init h from hidden[0] ----------------
__global__ void k_init_h(const float* __restrict__ hidden, float* __restrict__ hf,
                         ushort* __restrict__ hb) {
    int i = blockIdx.x * 256 + threadIdx.x;   // grid 256 -> 65536
    float v = hidden[i];
    hf[i] = v;
    hb[i] = f2bf(v);
}

// ---------------- K1: logits (dec|h)@Wa^T, gh = h@Whh^T, out[t-1] = h@Wo^T --------
__global__ __launch_bounds__(256) void k1(
    const ushort* __restrict__ tseqb, const ushort* __restrict__ hb,
    const ushort* __restrict__ Wab, const ushort* __restrict__ Whhb,
    const ushort* __restrict__ Wob,
    const float* __restrict__ ba, const float* __restrict__ bhh,
    const float* __restrict__ bo,
    float* __restrict__ logits, float* __restrict__ gh,
    float* __restrict__ out, int t)
{
    const int bx = blockIdx.x;
    const int wave = threadIdx.x >> 6;
    const int lane = threadIdx.x & 63;
    const int l15 = lane & 15;
    const int lg = lane >> 4;
    const s8v zf = {0, 0, 0, 0, 0, 0, 0, 0};
    f4v acc[4] = {};

    if (bx < 32) {
        // ---- logits: M=128 N=1024 K=1112, A = [dec_t | h] ----
        const int mt = bx & 1, ng = bx >> 1;
        const int mrow = mt * 64 + wave * 16;
        const int n0g = ng * 64;
        const int row = mrow + l15;
        for (int kc = 0; kc < 35; ++kc) {
            const int kb = kc * 32 + lg * 8;
            s8v a;
            if (kb >= KCAT) a = zf;
            else if (kb < VV) {
                if (t == 0) a = zf;
                else a = *(const s8v*)(tseqb + ((size_t)row * TT + (t - 1)) * VV + kb);
            } else {
                a = *(const s8v*)(hb + row * HH + (kb - VV));
            }
#pragma unroll
            for (int nt = 0; nt < 4; ++nt) {
                const int n = n0g + nt * 16 + l15;
                s8v b = (kb >= KCAT) ? zf : *(const s8v*)(Wab + (size_t)n * KCAT + kb);
                acc[nt] = __builtin_amdgcn_mfma_f32_16x16x32_bf16(a, b, acc[nt], 0, 0, 0);
            }
        }
#pragma unroll
        for (int nt = 0; nt < 4; ++nt) {
            const int n = n0g + nt * 16 + l15;
            const float bias = ba[n];
#pragma unroll
            for (int i = 0; i < 4; ++i) {
                const int m = mrow + lg * 4 + i;
                logits[m * SS + n] = acc[nt][i] + bias;
            }
        }
    } else if (bx < 80) {
        // ---- gh: M=128 N=1536 K=512, A = h ----
        const int ib = bx - 32;
        const int mt = ib & 1, ng = ib >> 1;
        const int mrow = mt * 64 + wave * 16;
        const int n0g = ng * 64;
        const int row = mrow + l15;
        for (int kc = 0; kc < 16; ++kc) {
            const int kb = kc * 32 + lg * 8;
            s8v a = *(const s8v*)(hb + row * HH + kb);
#pragma unroll
            for (int nt = 0; nt < 4; ++nt) {
                const int n = n0g + nt * 16 + l15;
                s8v b = *(const s8v*)(Whhb + (size_t)n * HH + kb);
                acc[nt] = __builtin_amdgcn_mfma_f32_16x16x32_bf16(a, b, acc[nt], 0, 0, 0);
            }
        }
#pragma unroll
        for (int nt = 0; nt < 4; ++nt) {
            const int n = n0g + nt * 16 + l15;
            const float bias = bhh[n];
#pragma unroll
            for (int i = 0; i < 4; ++i) {
                const int m = mrow + lg * 4 + i;
                gh[m * G3 + n] = acc[nt][i] + bias;
            }
        }
    } else {
        // ---- out[t-1]: M=128 N=600 K=512, A = h ----
        if (t == 0) return;
        const int ib = bx - 80;
        const int mt = ib & 1, ng = ib >> 1;   // ng in [0,10)
        const int mrow = mt * 64 + wave * 16;
        const int n0g = ng * 64;
        const int row = mrow + l15;
        for (int kc = 0; kc < 16; ++kc) {
            const int kb = kc * 32 + lg * 8;
            s8v a = *(const s8v*)(hb + row * HH + kb);
#pragma unroll
            for (int nt = 0; nt < 4; ++nt) {
                int n = n0g + nt * 16 + l15;
                if (n >= VV) n = VV - 1;        // clamp load, mask store
                s8v b = *(const s8v*)(Wob + (size_t)n * HH + kb);
                acc[nt] = __builtin_amdgcn_mfma_f32_16x16x32_bf16(a, b, acc[nt], 0, 0, 0);
            }
        }
#pragma unroll
        for (int nt = 0; nt < 4; ++nt) {
            const int n = n0g + nt * 16 + l15;
            if (n < VV) {
                const float bias = bo[n];
#pragma unroll
                for (int i = 0; i < 4; ++i) {
                    const int m = mrow + lg * 4 + i;
                    out[((size_t)m * TT + (t - 1)) * VV + n] = acc[nt][i] + bias;
                }
            }
        }
    }
}

// ---------------- K2: softmax(logits row) + attention partials ----------------
template <int EBF>
__global__ __launch_bounds__(256) void k2(
    const float* __restrict__ logits, const void* __restrict__ encp,
    float* __restrict__ part)
{
    const int b = blockIdx.y;
    const int sc = blockIdx.x;     // s-chunk 0..3 (256 rows each)
    const int tid = threadIdx.x;
    const int wave = tid >> 6;
    const int lane = tid & 63;
    __shared__ float aw[SS];
    __shared__ float red[256];
    __shared__ float redc[4][AA];

    float4 lv = *(const float4*)(logits + b * SS + tid * 4);
    float lmax = fmaxf(fmaxf(lv.x, lv.y), fmaxf(lv.z, lv.w));
    red[tid] = lmax;
    __syncthreads();
    for (int s = 128; s > 0; s >>= 1) {
        if (tid < s) red[tid] = fmaxf(red[tid], red[tid + s]);
        __syncthreads();
    }
    const float mx = red[0];
    __syncthreads();
    float e0 = __expf(lv.x - mx), e1 = __expf(lv.y - mx);
    float e2 = __expf(lv.z - mx), e3 = __expf(lv.w - mx);
    aw[tid * 4 + 0] = e0; aw[tid * 4 + 1] = e1;
    aw[tid * 4 + 2] = e2; aw[tid * 4 + 3] = e3;
    red[tid] = (e0 + e1) + (e2 + e3);
    __syncthreads();
    for (int s = 128; s > 0; s >>= 1) {
        if (tid < s) red[tid] += red[tid + s];
        __syncthreads();
    }
    const float inv = 1.0f / red[0];
    __syncthreads();

    float acc[8] = {0, 0, 0, 0, 0, 0, 0, 0};
    const int c0 = lane * 8;
    for (int p = 0; p < 64; ++p) {
        const int s = sc * 256 + p * 4 + wave;
        const float w = aw[s];
        if (EBF) {
            const ushort* rp = (const ushort*)encp + ((size_t)b * SS + s) * AA + c0;
            uint4 u = *(const uint4*)rp;
            acc[0] += w * bflo(u.x); acc[1] += w * bfhi(u.x);
            acc[2] += w * bflo(u.y); acc[3] += w * bfhi(u.y);
            acc[4] += w * bflo(u.z); acc[5] += w * bfhi(u.z);
            acc[6] += w * bflo(u.w); acc[7] += w * bfhi(u.w);
        } else {
            const float* rp = (const float*)encp + ((size_t)b * SS + s) * AA + c0;
            float4 v0 = *(const float4*)rp;
            float4 v1 = *(const float4*)(rp + 4);
            acc[0] += w * v0.x; acc[1] += w * v0.y; acc[2] += w * v0.z; acc[3] += w * v0.w;
            acc[4] += w * v1.x; acc[5] += w * v1.y; acc[6] += w * v1.z; acc[7] += w * v1.w;
        }
    }
#pragma unroll
    for (int j = 0; j < 8; ++j) redc[wave][c0 + j] = acc[j];
    __syncthreads();
    for (int c = tid; c < AA; c += 256) {
        float s = (redc[0][c] + redc[1][c]) + (redc[2][c] + redc[3][c]);
        part[((size_t)sc * BB + b) * AA + c] = s * inv;
    }
}

// ---------------- K3: gru_in = relu([dec_t | attn] @ Wc^T + bc), bf16 out --------
__global__ __launch_bounds__(256) void k3(
    const ushort* __restrict__ tseqb, const float* __restrict__ part,
    const ushort* __restrict__ Wcb, const float* __restrict__ bc,
    ushort* __restrict__ gruin, int t)
{
    const int bx = blockIdx.x;           // 16 blocks: 2 mt x 8 ng
    const int mt = bx & 1, ng = bx >> 1;
    const int wave = threadIdx.x >> 6, lane = threadIdx.x & 63;
    const int l15 = lane & 15, lg = lane >> 4;
    const int mrow = mt * 64 + wave * 16;
    const int n0g = ng * 64;
    const int row = mrow + l15;
    const s8v zf = {0, 0, 0, 0, 0, 0, 0, 0};
    f4v acc[4] = {};
    for (int kc = 0; kc < 35; ++kc) {
        const int kb = kc * 32 + lg * 8;
        s8v a;
        if (kb >= KCAT) a = zf;
        else if (kb < VV) {
            if (t == 0) a = zf;
            else a = *(const s8v*)(tseqb + ((size_t)row * TT + (t - 1)) * VV + kb);
        } else {
            const int ko = kb - VV;       // attn column (mult of 8)
            const float* p0 = part + ((size_t)0 * BB + row) * AA + ko;
            const float* p1 = part + ((size_t)1 * BB + row) * AA + ko;
            const float* p2 = part + ((size_t)2 * BB + row) * AA + ko;
            const float* p3 = part + ((size_t)3 * BB + row) * AA + ko;
            float4 a0 = *(const float4*)p0, b0 = *(const float4*)(p0 + 4);
            float4 a1 = *(const float4*)p1, b1 = *(const float4*)(p1 + 4);
            float4 a2 = *(const float4*)p2, b2 = *(const float4*)(p2 + 4);
            float4 a3 = *(const float4*)p3, b3 = *(const float4*)(p3 + 4);
            float s[8];
            s[0] = (a0.x + a1.x) + (a2.x + a3.x); s[1] = (a0.y + a1.y) + (a2.y + a3.y);
            s[2] = (a0.z + a1.z) + (a2.z + a3.z); s[3] = (a0.w + a1.w) + (a2.w + a3.w);
            s[4] = (b0.x + b1.x) + (b2.x + b3.x); s[5] = (b0.y + b1.y) + (b2.y + b3.y);
            s[6] = (b0.z + b1.z) + (b2.z + b3.z); s[7] = (b0.w + b1.w) + (b2.w + b3.w);
            union { s8v v; ushort u[8]; } tmp;
#pragma unroll
            for (int j = 0; j < 8; ++j) tmp.u[j] = f2bf(s[j]);
            a = tmp.v;
        }
#pragma unroll
        for (int nt = 0; nt < 4; ++nt) {
            const int n = n0g + nt * 16 + l15;
            s8v b = (kb >= KCAT) ? zf : *(const s8v*)(Wcb + (size_t)n * KCAT + kb);
            acc[nt] = __builtin_amdgcn_mfma_f32_16x16x32_bf16(a, b, acc[nt], 0, 0, 0);
        }
    }
#pragma unroll
    for (int nt = 0; nt < 4; ++nt) {
        const int n = n0g + nt * 16 + l15;
        const float bias = bc[n];
#pragma unroll
        for (int i = 0; i < 4; ++i) {
            const int m = mrow + lg * 4 + i;
            float v = acc[nt][i] + bias;
            v = v > 0.0f ? v : 0.0f;
            gruin[m * HH + n] = f2bf(v);
        }
    }
}

// ---------------- K4: gi = gru_in @ Wih^T (+bih) ; GRU gates ; h_new ----------
__global__ __launch_bounds__(256) void k4(
    const ushort* __restrict__ gruin, const ushort* __restrict__ Wihb,
    const float* __restrict__ bih, const float* __restrict__ gh,
    const float* __restrict__ hf, float* __restrict__ hnf,
    ushort* __restrict__ hnb)
{
    const int bx = blockIdx.x;            // 16 blocks: 2 mt x 8 ng (j in [0,512))
    const int mt = bx & 1, ng = bx >> 1;
    const int wave = threadIdx.x >> 6, lane = threadIdx.x & 63;
    const int l15 = lane & 15, lg = lane >> 4;
    const int mrow = mt * 64 + wave * 16;
    const int n0g = ng * 64;
    const int row = mrow + l15;
    f4v ar[4] = {}, az[4] = {}, an[4] = {};
    for (int kc = 0; kc < 16; ++kc) {
        const int kb = kc * 32 + lg * 8;
        s8v a = *(const s8v*)(gruin + row * HH + kb);
#pragma unroll
        for (int nt = 0; nt < 4; ++nt) {
            const int n = n0g + nt * 16 + l15;
            s8v br = *(const s8v*)(Wihb + (size_t)(n)        * HH + kb);
            s8v bz = *(const s8v*)(Wihb + (size_t)(HH + n)   * HH + kb);
            s8v bn = *(const s8v*)(Wihb + (size_t)(2*HH + n) * HH + kb);
            ar[nt] = __builtin_amdgcn_mfma_f32_16x16x32_bf16(a, br, ar[nt], 0, 0, 0);
            az[nt] = __builtin_amdgcn_mfma_f32_16x16x32_bf16(a, bz, az[nt], 0, 0, 0);
            an[nt] = __builtin_amdgcn_mfma_f32_16x16x32_bf16(a, bn, an[nt], 0, 0, 0);
        }
    }
#pragma unroll
    for (int nt = 0; nt < 4; ++nt) {
        const int j = n0g + nt * 16 + l15;
        const float br_ = bih[j], bz_ = bih[HH + j], bn_ = bih[2 * HH + j];
#pragma unroll
        for (int i = 0; i < 4; ++i) {
            const int m = mrow + lg * 4 + i;
            const float* ghm = gh + (size_t)m * G3;
            float gr = ar[nt][i] + br_ + ghm[j];
            float gz = az[nt][i] + bz_ + ghm[HH + j];
            float r = 1.0f / (1.0f + __expf(-gr));
            float z = 1.0f / (1.0f + __expf(-gz));
            float nn = tanhf(an[nt][i] + bn_ + r * ghm[2 * HH + j]);
            float hold = hf[m * HH + j];
            float hv = (1.0f - z) * nn + z * hold;
            hnf[m * HH + j] = hv;
            hnb[m * HH + j] = f2bf(hv);
        }
    }
}

// ---------------- tail: out[149] = h_final @ Wo^T + bo ; copy h_final ----------
__global__ __launch_bounds__(256) void k_tail(
    const ushort* __restrict__ hb, const float* __restrict__ hf,
    const ushort* __restrict__ Wob, const float* __restrict__ bo,
    float* __restrict__ out)
{
    const int bx = blockIdx.x;
    if (bx >= 20) {
        const int i = (bx - 20) * 1024 + threadIdx.x * 4;  // 64 blocks -> 65536
        float4 v = *(const float4*)(hf + i);
        *(float4*)(out + (size_t)BB * TT * VV + i) = v;
        return;
    }
    const int mt = bx & 1, ng = bx >> 1;
    const int wave = threadIdx.x >> 6, lane = threadIdx.x & 63;
    const int l15 = lane & 15, lg = lane >> 4;
    const int mrow = mt * 64 + wave * 16;
    const int n0g = ng * 64;
    const int row = mrow + l15;
    f4v acc[4] = {};
    for (int kc = 0; kc < 16; ++kc) {
        const int kb = kc * 32 + lg * 8;
        s8v a = *(const s8v*)(hb + row * HH + kb);
#pragma unroll
        for (int nt = 0; nt < 4; ++nt) {
            int n = n0g + nt * 16 + l15;
            if (n >= VV) n = VV - 1;
            s8v b = *(const s8v*)(Wob + (size_t)n * HH + kb);
            acc[nt] = __builtin_amdgcn_mfma_f32_16x16x32_bf16(a, b, acc[nt], 0, 0, 0);
        }
    }
#pragma unroll
    for (int nt = 0; nt < 4; ++nt) {
        const int n = n0g + nt * 16 + l15;
        if (n < VV) {
            const float bias = bo[n];
#pragma unroll
            for (int i = 0; i < 4; ++i) {
                const int m = mrow + lg * 4 + i;
                out[((size_t)m * TT + (TT - 1)) * VV + n] = acc[nt][i] + bias;
            }
        }
    }
}

// ------------------------------- host -------------------------------
extern "C" void kernel_launch(void* const* d_in, const int* in_sizes, int n_in,
                              void* d_out, int out_size, void* d_ws, size_t ws_size,
                              hipStream_t stream)
{
    const float* enc    = (const float*)d_in[0];
    const float* hidden = (const float*)d_in[1];
    const float* tseq   = (const float*)d_in[2];
    // d_in[3] = max_length (fixed at TT)
    const float* Wa  = (const float*)d_in[4];
    const float* ba  = (const float*)d_in[5];
    const float* Wc  = (const float*)d_in[6];
    const float* bc  = (const float*)d_in[7];
    const float* Wih = (const float*)d_in[8];
    const float* Whh = (const float*)d_in[9];
    const float* bih = (const float*)d_in[10];
    const float* bhh = (const float*)d_in[11];
    const float* Wo  = (const float*)d_in[12];
    const float* bo  = (const float*)d_in[13];
    float* out = (float*)d_out;

    char* w = (char*)d_ws;
    size_t off = 0;
    auto alloc = [&](size_t bytes) {
        void* p = w + off;
        off += (bytes + 255) & ~(size_t)255;
        return p;
    };
    float*  logits = (float*)alloc((size_t)BB * SS * 4);
    float*  ghb    = (float*)alloc((size_t)BB * G3 * 4);
    float*  part   = (float*)alloc((size_t)4 * BB * AA * 4);
    float*  h_f0   = (float*)alloc((size_t)BB * HH * 4);
    float*  h_f1   = (float*)alloc((size_t)BB * HH * 4);
    ushort* h_b0   = (ushort*)alloc((size_t)BB * HH * 2);
    ushort* h_b1   = (ushort*)alloc((size_t)BB * HH * 2);
    ushort* gruin  = (ushort*)alloc((size_t)BB * HH * 2);
    ushort* tseqb  = (ushort*)alloc((size_t)BB * TT * VV * 2);
    ushort* Wab    = (ushort*)alloc((size_t)SS * KCAT * 2);
    ushort* Wcb    = (ushort*)alloc((size_t)HH * KCAT * 2);
    ushort* Wihb   = (ushort*)alloc((size_t)G3 * HH * 2);
    ushort* Whhb   = (ushort*)alloc((size_t)G3 * HH * 2);
    ushort* Wob    = (ushort*)alloc((size_t)VV * HH * 2);
    const size_t enc_elems = (size_t)BB * SS * AA;
    const bool encbf = (off + enc_elems * 2) <= ws_size;
    ushort* encb = encbf ? (ushort*)alloc(enc_elems * 2) : nullptr;

    auto cvt = [&](const float* s, ushort* d, long n) {
        long n4 = n / 4;
        int blocks = (int)((n4 + 255) / 256);
        if (blocks > 4096) blocks = 4096;
        k_cvt4<<<blocks, 256, 0, stream>>>((const float4*)s, d, n4);
    };
    cvt(tseq, tseqb, (long)BB * TT * VV);
    cvt(Wa,  Wab,  (long)SS * KCAT);
    cvt(Wc,  Wcb,  (long)HH * KCAT);
    cvt(Wih, Wihb, (long)G3 * HH);
    cvt(Whh, Whhb, (long)G3 * HH);
    cvt(Wo,  Wob,  (long)VV * HH);
    if (encbf) cvt(enc, encb, (long)enc_elems);

    k_init_h<<<256, 256, 0, stream>>>(hidden, h_f0, h_b0);

    for (int t = 0; t < TT; ++t) {
        float*  hf  = (t & 1) ? h_f1 : h_f0;
        ushort* hb  = (t & 1) ? h_b1 : h_b0;
        float*  hfn = (t & 1) ? h_f0 : h_f1;
        ushort* hbn = (t & 1) ? h_b0 : h_b1;

        k1<<<100, 256, 0, stream>>>(tseqb, hb, Wab, Whhb, Wob, ba, bhh, bo,
                                    logits, ghb, out, t);
        if (encbf)
            k2<1><<<dim3(4, BB), 256, 0, stream>>>(logits, (const void*)encb, part);
        else
            k2<0><<<dim3(4, BB), 256, 0, stream>>>(logits, (const void*)enc, part);
        k3<<<16, 256, 0, stream>>>(tseqb, part, Wcb, bc, gruin, t);
        k4<<<16, 256, 0, stream>>>(gruin, Wihb, bih, ghb, hf, hfn, hbn);
    }
    // after 150 steps (even count) final h is in h_f0 / h_b0
    k_tail<<<84, 256, 0, stream>>>(h_b0, h_f0, Wob, bo, out);
}